// Round 10
// baseline (170.077 us; speedup 1.0000x reference)
//
#include <hip/hip_runtime.h>
#include <math.h>

#define QD 24
#define KD 24
#define HD 64
#define NN 512
#define DO 128

typedef float v4f __attribute__((ext_vector_type(4)));

__device__ __forceinline__ float fast_tanh(float x) {
    // tanh(x) = sign(x) * (1 - e^{-2|x|}) / (1 + e^{-2|x|}); exp via exp2
    float ax = __builtin_fabsf(x);
    float t  = __builtin_amdgcn_exp2f(-2.885390081777927f * ax); // -2*log2(e)*|x|
    float r  = (1.0f - t) * __builtin_amdgcn_rcpf(1.0f + t);
    return __builtin_copysignf(r, x);
}

// One 256-thread block per b. Barrier-free fused main loop (R7) + NT loads
// for the TO stream (R9 win). This round: 6 waves/SIMD occupancy (smoother
// cross-block phase mixing), deferred round-1 pwp load (lower VGPR peak),
// NT output stores. pwp loads stay cached: 96B rows straddle lines across
// consecutive instructions, NT would break that reuse.
__global__ __launch_bounds__(256, 6) void fused_attn(
    const float* __restrict__ fwp,   // [B, 24]
    const float* __restrict__ pwp,   // [B, N, 24]
    const float* __restrict__ to,    // [B, N, 128]
    const float* __restrict__ wq1, const float* __restrict__ bq1,
    const float* __restrict__ wq2, const float* __restrict__ bq2,
    const float* __restrict__ wk1, const float* __restrict__ bk1,
    const float* __restrict__ wk2,
    float* __restrict__ out_ctx,     // [B, 128]
    float* __restrict__ out_attn)    // [B, N]
{
    const int b    = blockIdx.x;
    const int t    = threadIdx.x;
    const int wave = t >> 6;
    const int lane = t & 63;
    const int g    = lane & 31;      // float4 column 0..31
    const int h    = lane >> 5;      // half-wave 0/1

    __shared__ float  qks[HD];
    __shared__ float  h1s[HD];
    __shared__ float  qvs[HD];
    __shared__ float  s_attn[NN];    // unnormalized p for all rows
    __shared__ float  s_red[4];
    __shared__ v4f    s_part[8][32];

    const int n0 = wave * 64 + lane;         // round-0 row
    const int n1 = n0 + 4 * 64;              // round-1 row

    // issue round-0 pwp loads immediately (complete under prologue)
    const float* prow0 = pwp + ((size_t)b * NN + n0) * KD;
    float x[KD];
#pragma unroll
    for (int i = 0; i < KD / 4; ++i)
        reinterpret_cast<v4f*>(x)[i] = reinterpret_cast<const v4f*>(prow0)[i];

    // ---------- prologue: Q-path on threads t<64 ----------
    if (t < HD) {
        float xf[QD];
#pragma unroll
        for (int i = 0; i < QD / 4; ++i)
            reinterpret_cast<v4f*>(xf)[i] =
                reinterpret_cast<const v4f*>(fwp + (size_t)b * QD)[i];
        float a = bq1[t];
#pragma unroll
        for (int k = 0; k < QD; ++k) a = fmaf(xf[k], wq1[k * HD + t], a);
        h1s[t] = fast_tanh(a);
    }
    __syncthreads();
    if (t < HD) {
        float a = bq2[t];
#pragma unroll
        for (int i = 0; i < HD; ++i) a = fmaf(h1s[i], wq2[i * HD + t], a);
        qvs[t] = a;
    }
    __syncthreads();
    if (t < HD) {
        float s = 0.0f;
#pragma unroll
        for (int hh = 0; hh < HD; ++hh) s = fmaf(wk2[t * HD + hh], qvs[hh], s);
        qks[t] = s * 0.18033688011112042f;   // (1/8) * log2(e)
    }
    __syncthreads();

    float Mb = 0.0f;                 // fixed softmax shift (upper bound)
#pragma unroll
    for (int hh = 0; hh < HD; ++hh) Mb += __builtin_fabsf(qks[hh]);

    const v4f* wk1_4 = reinterpret_cast<const v4f*>(wk1);
    const v4f* bk1_4 = reinterpret_cast<const v4f*>(bk1);
    const v4f* qks_4 = reinterpret_cast<const v4f*>(qks);
    const v4f* trow  = reinterpret_cast<const v4f*>(to + (size_t)b * NN * DO) + g;

    v4f acc = (v4f){0.f, 0.f, 0.f, 0.f};
    float Lloc = 0.0f;

    auto score_one = [&](const float* xr) -> float {
        float sc = 0.0f;
#pragma unroll 2
        for (int j4 = 0; j4 < HD / 4; ++j4) {
            v4f bb = bk1_4[j4];                       // uniform -> scalar
            float a0 = bb.x, a1 = bb.y, a2 = bb.z, a3 = bb.w;
#pragma unroll
            for (int k = 0; k < KD; ++k) {
                v4f w = wk1_4[k * (HD / 4) + j4];     // uniform -> scalar
                a0 = fmaf(xr[k], w.x, a0); a1 = fmaf(xr[k], w.y, a1);
                a2 = fmaf(xr[k], w.z, a2); a3 = fmaf(xr[k], w.w, a3);
            }
            v4f qq = qks_4[j4];                       // LDS broadcast
            sc = fmaf(fast_tanh(a0), qq.x, sc);
            sc = fmaf(fast_tanh(a1), qq.y, sc);
            sc = fmaf(fast_tanh(a2), qq.z, sc);
            sc = fmaf(fast_tanh(a3), qq.w, sc);
        }
        return sc;
    };

    auto stream_chunk = [&](int chunk) {
        const int base = chunk * 64;
#pragma unroll 8
        for (int i = 0; i < 32; ++i) {
            const int row = base + 2 * i + h;
            const float p = s_attn[row];   // 2 addrs/wave -> LDS broadcast
            v4f v = __builtin_nontemporal_load(&trow[(size_t)row * (DO / 4)]);
            acc.x = fmaf(p, v.x, acc.x);
            acc.y = fmaf(p, v.y, acc.y);
            acc.z = fmaf(p, v.z, acc.z);
            acc.w = fmaf(p, v.w, acc.w);
        }
    };

    // ---------- round 0 ----------
    const float p0 = __builtin_amdgcn_exp2f(score_one(x) - Mb);
    s_attn[n0] = p0;                 // same-wave DS ordering; no barrier
    Lloc += p0;

    stream_chunk(wave);

    // round-1 pwp row (deferred: keeps x/x1 from being live together;
    // latency hides under co-resident waves' streaming)
    const float* prow1 = pwp + ((size_t)b * NN + n1) * KD;
#pragma unroll
    for (int i = 0; i < KD / 4; ++i)
        reinterpret_cast<v4f*>(x)[i] = reinterpret_cast<const v4f*>(prow1)[i];

    // ---------- round 1 ----------
    const float p1 = __builtin_amdgcn_exp2f(score_one(x) - Mb);
    s_attn[n1] = p1;
    Lloc += p1;
    stream_chunk(wave + 4);

    // ---------- epilogue ----------
#pragma unroll
    for (int o = 32; o > 0; o >>= 1) Lloc += __shfl_xor(Lloc, o, 64);
    if (lane == 0) s_red[wave] = Lloc;
    s_part[wave * 2 + h][g] = acc;
    __syncthreads();

    const float L    = (s_red[0] + s_red[1]) + (s_red[2] + s_red[3]);
    const float invL = __builtin_amdgcn_rcpf(L);

    __builtin_nontemporal_store(s_attn[t] * invL,
                                out_attn + (size_t)b * NN + t);
    __builtin_nontemporal_store(s_attn[t + 256] * invL,
                                out_attn + (size_t)b * NN + t + 256);

    if (t < 32) {
        v4f r = s_part[0][t];
#pragma unroll
        for (int q = 1; q < 8; ++q) {
            v4f v = s_part[q][t];
            r.x += v.x; r.y += v.y; r.z += v.z; r.w += v.w;
        }
        v4f o;
        o.x = r.x * invL; o.y = r.y * invL; o.z = r.z * invL; o.w = r.w * invL;
        __builtin_nontemporal_store(o,
            reinterpret_cast<v4f*>(out_ctx + (size_t)b * DO) + t);
    }
}

extern "C" void kernel_launch(void* const* d_in, const int* in_sizes, int n_in,
                              void* d_out, int out_size, void* d_ws, size_t ws_size,
                              hipStream_t stream) {
    const float* fwp = (const float*)d_in[0];
    const float* pwp = (const float*)d_in[1];
    const float* to  = (const float*)d_in[2];
    const float* wq1 = (const float*)d_in[3];
    const float* bq1 = (const float*)d_in[4];
    const float* wq2 = (const float*)d_in[5];
    const float* bq2 = (const float*)d_in[6];
    const float* wk1 = (const float*)d_in[7];
    const float* bk1 = (const float*)d_in[8];
    const float* wk2 = (const float*)d_in[9];
    // d_in[10] = bk2: per-row constant in scores -> cancels in softmax.

    float* out  = (float*)d_out;
    const int B = in_sizes[0] / QD;  // 2048

    fused_attn<<<B, 256, 0, stream>>>(fwp, pwp, to, wq1, bq1, wq2, bq2,
                                      wk1, bk1, wk2,
                                      out, out + (size_t)B * DO);
}

// Round 11
// 128.233 us; speedup vs baseline: 1.3263x; 1.3263x over previous
//
#include <hip/hip_runtime.h>
#include <math.h>

#define QD 24
#define KD 24
#define HD 64
#define NN 512
#define DO 128

typedef float v4f __attribute__((ext_vector_type(4)));

__device__ __forceinline__ float fast_tanh(float x) {
    // tanh(x) = sign(x) * (1 - e^{-2|x|}) / (1 + e^{-2|x|}); exp via exp2
    float ax = __builtin_fabsf(x);
    float t  = __builtin_amdgcn_exp2f(-2.885390081777927f * ax); // -2*log2(e)*|x|
    float r  = (1.0f - t) * __builtin_amdgcn_rcpf(1.0f + t);
    return __builtin_copysignf(r, x);
}

// One 256-thread block per b. Barrier-free fused main loop (R7) + NT loads
// for the TO stream (R9, verified −16us). R11: exact R9 structure
// (launch_bounds(256,4), early x1 prefetch in separate regs) + NT applied
// to the remaining read-once/write-once traffic: pwp loads, output stores.
__global__ __launch_bounds__(256, 4) void fused_attn(
    const float* __restrict__ fwp,   // [B, 24]
    const float* __restrict__ pwp,   // [B, N, 24]
    const float* __restrict__ to,    // [B, N, 128]
    const float* __restrict__ wq1, const float* __restrict__ bq1,
    const float* __restrict__ wq2, const float* __restrict__ bq2,
    const float* __restrict__ wk1, const float* __restrict__ bk1,
    const float* __restrict__ wk2,
    float* __restrict__ out_ctx,     // [B, 128]
    float* __restrict__ out_attn)    // [B, N]
{
    const int b    = blockIdx.x;
    const int t    = threadIdx.x;
    const int wave = t >> 6;
    const int lane = t & 63;
    const int g    = lane & 31;      // float4 column 0..31
    const int h    = lane >> 5;      // half-wave 0/1

    __shared__ float  qks[HD];
    __shared__ float  h1s[HD];
    __shared__ float  qvs[HD];
    __shared__ float  s_attn[NN];    // unnormalized p for all rows
    __shared__ float  s_red[4];
    __shared__ v4f    s_part[8][32];

    const int n0 = wave * 64 + lane;         // round-0 row
    const int n1 = n0 + 4 * 64;              // round-1 row

    // issue round-0 pwp loads immediately (complete under prologue)
    const float* prow0 = pwp + ((size_t)b * NN + n0) * KD;
    float x[KD];
#pragma unroll
    for (int i = 0; i < KD / 4; ++i)
        reinterpret_cast<v4f*>(x)[i] = __builtin_nontemporal_load(
            reinterpret_cast<const v4f*>(prow0) + i);

    // ---------- prologue: Q-path on threads t<64 ----------
    if (t < HD) {
        float xf[QD];
#pragma unroll
        for (int i = 0; i < QD / 4; ++i)
            reinterpret_cast<v4f*>(xf)[i] =
                reinterpret_cast<const v4f*>(fwp + (size_t)b * QD)[i];
        float a = bq1[t];
#pragma unroll
        for (int k = 0; k < QD; ++k) a = fmaf(xf[k], wq1[k * HD + t], a);
        h1s[t] = fast_tanh(a);
    }
    __syncthreads();
    if (t < HD) {
        float a = bq2[t];
#pragma unroll
        for (int i = 0; i < HD; ++i) a = fmaf(h1s[i], wq2[i * HD + t], a);
        qvs[t] = a;
    }
    __syncthreads();
    if (t < HD) {
        float s = 0.0f;
#pragma unroll
        for (int hh = 0; hh < HD; ++hh) s = fmaf(wk2[t * HD + hh], qvs[hh], s);
        qks[t] = s * 0.18033688011112042f;   // (1/8) * log2(e)
    }
    __syncthreads();

    float Mb = 0.0f;                 // fixed softmax shift (upper bound)
#pragma unroll
    for (int hh = 0; hh < HD; ++hh) Mb += __builtin_fabsf(qks[hh]);

    const v4f* wk1_4 = reinterpret_cast<const v4f*>(wk1);
    const v4f* bk1_4 = reinterpret_cast<const v4f*>(bk1);
    const v4f* qks_4 = reinterpret_cast<const v4f*>(qks);
    const v4f* trow  = reinterpret_cast<const v4f*>(to + (size_t)b * NN * DO) + g;

    v4f acc = (v4f){0.f, 0.f, 0.f, 0.f};
    float Lloc = 0.0f;

    auto score_one = [&](const float* xr) -> float {
        float sc = 0.0f;
#pragma unroll 2
        for (int j4 = 0; j4 < HD / 4; ++j4) {
            v4f bb = bk1_4[j4];                       // uniform -> scalar
            float a0 = bb.x, a1 = bb.y, a2 = bb.z, a3 = bb.w;
#pragma unroll
            for (int k = 0; k < KD; ++k) {
                v4f w = wk1_4[k * (HD / 4) + j4];     // uniform -> scalar
                a0 = fmaf(xr[k], w.x, a0); a1 = fmaf(xr[k], w.y, a1);
                a2 = fmaf(xr[k], w.z, a2); a3 = fmaf(xr[k], w.w, a3);
            }
            v4f qq = qks_4[j4];                       // LDS broadcast
            sc = fmaf(fast_tanh(a0), qq.x, sc);
            sc = fmaf(fast_tanh(a1), qq.y, sc);
            sc = fmaf(fast_tanh(a2), qq.z, sc);
            sc = fmaf(fast_tanh(a3), qq.w, sc);
        }
        return sc;
    };

    auto stream_chunk = [&](int chunk) {
        const int base = chunk * 64;
#pragma unroll 8
        for (int i = 0; i < 32; ++i) {
            const int row = base + 2 * i + h;
            const float p = s_attn[row];   // 2 addrs/wave -> LDS broadcast
            v4f v = __builtin_nontemporal_load(&trow[(size_t)row * (DO / 4)]);
            acc.x = fmaf(p, v.x, acc.x);
            acc.y = fmaf(p, v.y, acc.y);
            acc.z = fmaf(p, v.z, acc.z);
            acc.w = fmaf(p, v.w, acc.w);
        }
    };

    // ---------- round 0 ----------
    const float p0 = __builtin_amdgcn_exp2f(score_one(x) - Mb);
    s_attn[n0] = p0;                 // same-wave DS ordering; no barrier
    Lloc += p0;

    // prefetch round-1 pwp row into separate regs (hides under chunk-0 stream)
    const float* prow1 = pwp + ((size_t)b * NN + n1) * KD;
    float x1[KD];
#pragma unroll
    for (int i = 0; i < KD / 4; ++i)
        reinterpret_cast<v4f*>(x1)[i] = __builtin_nontemporal_load(
            reinterpret_cast<const v4f*>(prow1) + i);

    stream_chunk(wave);

    // ---------- round 1 ----------
    const float p1 = __builtin_amdgcn_exp2f(score_one(x1) - Mb);
    s_attn[n1] = p1;
    Lloc += p1;
    stream_chunk(wave + 4);

    // ---------- epilogue ----------
#pragma unroll
    for (int o = 32; o > 0; o >>= 1) Lloc += __shfl_xor(Lloc, o, 64);
    if (lane == 0) s_red[wave] = Lloc;
    s_part[wave * 2 + h][g] = acc;
    __syncthreads();

    const float L    = (s_red[0] + s_red[1]) + (s_red[2] + s_red[3]);
    const float invL = __builtin_amdgcn_rcpf(L);

    __builtin_nontemporal_store(s_attn[t] * invL,
                                out_attn + (size_t)b * NN + t);
    __builtin_nontemporal_store(s_attn[t + 256] * invL,
                                out_attn + (size_t)b * NN + t + 256);

    if (t < 32) {
        v4f r = s_part[0][t];
#pragma unroll
        for (int q = 1; q < 8; ++q) {
            v4f v = s_part[q][t];
            r.x += v.x; r.y += v.y; r.z += v.z; r.w += v.w;
        }
        v4f o;
        o.x = r.x * invL; o.y = r.y * invL; o.z = r.z * invL; o.w = r.w * invL;
        __builtin_nontemporal_store(o,
            reinterpret_cast<v4f*>(out_ctx + (size_t)b * DO) + t);
    }
}

extern "C" void kernel_launch(void* const* d_in, const int* in_sizes, int n_in,
                              void* d_out, int out_size, void* d_ws, size_t ws_size,
                              hipStream_t stream) {
    const float* fwp = (const float*)d_in[0];
    const float* pwp = (const float*)d_in[1];
    const float* to  = (const float*)d_in[2];
    const float* wq1 = (const float*)d_in[3];
    const float* bq1 = (const float*)d_in[4];
    const float* wq2 = (const float*)d_in[5];
    const float* bq2 = (const float*)d_in[6];
    const float* wk1 = (const float*)d_in[7];
    const float* bk1 = (const float*)d_in[8];
    const float* wk2 = (const float*)d_in[9];
    // d_in[10] = bk2: per-row constant in scores -> cancels in softmax.

    float* out  = (float*)d_out;
    const int B = in_sizes[0] / QD;  // 2048

    fused_attn<<<B, 256, 0, stream>>>(fwp, pwp, to, wq1, bq1, wq2, bq2,
                                      wk1, bk1, wk2,
                                      out, out + (size_t)B * DO);
}

// Round 12
// 116.584 us; speedup vs baseline: 1.4588x; 1.0999x over previous
//
#include <hip/hip_runtime.h>
#include <math.h>

#define QD 24
#define KD 24
#define HD 64
#define NN 512
#define DO 128

typedef float v4f __attribute__((ext_vector_type(4)));

__device__ __forceinline__ float fast_tanh(float x) {
    // tanh(x) = sign(x) * (1 - e^{-2|x|}) / (1 + e^{-2|x|}); exp via exp2
    float ax = __builtin_fabsf(x);
    float t  = __builtin_amdgcn_exp2f(-2.885390081777927f * ax); // -2*log2(e)*|x|
    float r  = (1.0f - t) * __builtin_amdgcn_rcpf(1.0f + t);
    return __builtin_copysignf(r, x);
}

// One 256-thread block per b. Barrier-free fused main loop (R7) + NT loads
// for the 537MB TO stream (R9, verified -16us). R12 = R9 exactly, plus NT
// output stores ONLY. pwp loads stay CACHED: 96B rows straddle 128B lines
// across consecutive load instructions; NT there re-fetches lines and
// inflated pwp traffic ~2x (R11 regression, -12us).
__global__ __launch_bounds__(256, 4) void fused_attn(
    const float* __restrict__ fwp,   // [B, 24]
    const float* __restrict__ pwp,   // [B, N, 24]
    const float* __restrict__ to,    // [B, N, 128]
    const float* __restrict__ wq1, const float* __restrict__ bq1,
    const float* __restrict__ wq2, const float* __restrict__ bq2,
    const float* __restrict__ wk1, const float* __restrict__ bk1,
    const float* __restrict__ wk2,
    float* __restrict__ out_ctx,     // [B, 128]
    float* __restrict__ out_attn)    // [B, N]
{
    const int b    = blockIdx.x;
    const int t    = threadIdx.x;
    const int wave = t >> 6;
    const int lane = t & 63;
    const int g    = lane & 31;      // float4 column 0..31
    const int h    = lane >> 5;      // half-wave 0/1

    __shared__ float  qks[HD];
    __shared__ float  h1s[HD];
    __shared__ float  qvs[HD];
    __shared__ float  s_attn[NN];    // unnormalized p for all rows
    __shared__ float  s_red[4];
    __shared__ v4f    s_part[8][32];

    const int n0 = wave * 64 + lane;         // round-0 row
    const int n1 = n0 + 4 * 64;              // round-1 row

    // issue round-0 pwp loads immediately (complete under prologue); CACHED
    const float* prow0 = pwp + ((size_t)b * NN + n0) * KD;
    float x[KD];
#pragma unroll
    for (int i = 0; i < KD / 4; ++i)
        reinterpret_cast<v4f*>(x)[i] = reinterpret_cast<const v4f*>(prow0)[i];

    // ---------- prologue: Q-path on threads t<64 ----------
    if (t < HD) {
        float xf[QD];
#pragma unroll
        for (int i = 0; i < QD / 4; ++i)
            reinterpret_cast<v4f*>(xf)[i] =
                reinterpret_cast<const v4f*>(fwp + (size_t)b * QD)[i];
        float a = bq1[t];
#pragma unroll
        for (int k = 0; k < QD; ++k) a = fmaf(xf[k], wq1[k * HD + t], a);
        h1s[t] = fast_tanh(a);
    }
    __syncthreads();
    if (t < HD) {
        float a = bq2[t];
#pragma unroll
        for (int i = 0; i < HD; ++i) a = fmaf(h1s[i], wq2[i * HD + t], a);
        qvs[t] = a;
    }
    __syncthreads();
    if (t < HD) {
        float s = 0.0f;
#pragma unroll
        for (int hh = 0; hh < HD; ++hh) s = fmaf(wk2[t * HD + hh], qvs[hh], s);
        qks[t] = s * 0.18033688011112042f;   // (1/8) * log2(e)
    }
    __syncthreads();

    float Mb = 0.0f;                 // fixed softmax shift (upper bound)
#pragma unroll
    for (int hh = 0; hh < HD; ++hh) Mb += __builtin_fabsf(qks[hh]);

    const v4f* wk1_4 = reinterpret_cast<const v4f*>(wk1);
    const v4f* bk1_4 = reinterpret_cast<const v4f*>(bk1);
    const v4f* qks_4 = reinterpret_cast<const v4f*>(qks);
    const v4f* trow  = reinterpret_cast<const v4f*>(to + (size_t)b * NN * DO) + g;

    v4f acc = (v4f){0.f, 0.f, 0.f, 0.f};
    float Lloc = 0.0f;

    auto score_one = [&](const float* xr) -> float {
        float sc = 0.0f;
#pragma unroll 2
        for (int j4 = 0; j4 < HD / 4; ++j4) {
            v4f bb = bk1_4[j4];                       // uniform -> scalar
            float a0 = bb.x, a1 = bb.y, a2 = bb.z, a3 = bb.w;
#pragma unroll
            for (int k = 0; k < KD; ++k) {
                v4f w = wk1_4[k * (HD / 4) + j4];     // uniform -> scalar
                a0 = fmaf(xr[k], w.x, a0); a1 = fmaf(xr[k], w.y, a1);
                a2 = fmaf(xr[k], w.z, a2); a3 = fmaf(xr[k], w.w, a3);
            }
            v4f qq = qks_4[j4];                       // LDS broadcast
            sc = fmaf(fast_tanh(a0), qq.x, sc);
            sc = fmaf(fast_tanh(a1), qq.y, sc);
            sc = fmaf(fast_tanh(a2), qq.z, sc);
            sc = fmaf(fast_tanh(a3), qq.w, sc);
        }
        return sc;
    };

    auto stream_chunk = [&](int chunk) {
        const int base = chunk * 64;
#pragma unroll 8
        for (int i = 0; i < 32; ++i) {
            const int row = base + 2 * i + h;
            const float p = s_attn[row];   // 2 addrs/wave -> LDS broadcast
            v4f v = __builtin_nontemporal_load(&trow[(size_t)row * (DO / 4)]);
            acc.x = fmaf(p, v.x, acc.x);
            acc.y = fmaf(p, v.y, acc.y);
            acc.z = fmaf(p, v.z, acc.z);
            acc.w = fmaf(p, v.w, acc.w);
        }
    };

    // ---------- round 0 ----------
    const float p0 = __builtin_amdgcn_exp2f(score_one(x) - Mb);
    s_attn[n0] = p0;                 // same-wave DS ordering; no barrier
    Lloc += p0;

    // prefetch round-1 pwp row into separate regs (hides under chunk-0
    // stream); CACHED loads
    const float* prow1 = pwp + ((size_t)b * NN + n1) * KD;
    float x1[KD];
#pragma unroll
    for (int i = 0; i < KD / 4; ++i)
        reinterpret_cast<v4f*>(x1)[i] = reinterpret_cast<const v4f*>(prow1)[i];

    stream_chunk(wave);

    // ---------- round 1 ----------
    const float p1 = __builtin_amdgcn_exp2f(score_one(x1) - Mb);
    s_attn[n1] = p1;
    Lloc += p1;
    stream_chunk(wave + 4);

    // ---------- epilogue ----------
#pragma unroll
    for (int o = 32; o > 0; o >>= 1) Lloc += __shfl_xor(Lloc, o, 64);
    if (lane == 0) s_red[wave] = Lloc;
    s_part[wave * 2 + h][g] = acc;
    __syncthreads();

    const float L    = (s_red[0] + s_red[1]) + (s_red[2] + s_red[3]);
    const float invL = __builtin_amdgcn_rcpf(L);

    __builtin_nontemporal_store(s_attn[t] * invL,
                                out_attn + (size_t)b * NN + t);
    __builtin_nontemporal_store(s_attn[t + 256] * invL,
                                out_attn + (size_t)b * NN + t + 256);

    if (t < 32) {
        v4f r = s_part[0][t];
#pragma unroll
        for (int q = 1; q < 8; ++q) {
            v4f v = s_part[q][t];
            r.x += v.x; r.y += v.y; r.z += v.z; r.w += v.w;
        }
        v4f o;
        o.x = r.x * invL; o.y = r.y * invL; o.z = r.z * invL; o.w = r.w * invL;
        __builtin_nontemporal_store(o,
            reinterpret_cast<v4f*>(out_ctx + (size_t)b * DO) + t);
    }
}

extern "C" void kernel_launch(void* const* d_in, const int* in_sizes, int n_in,
                              void* d_out, int out_size, void* d_ws, size_t ws_size,
                              hipStream_t stream) {
    const float* fwp = (const float*)d_in[0];
    const float* pwp = (const float*)d_in[1];
    const float* to  = (const float*)d_in[2];
    const float* wq1 = (const float*)d_in[3];
    const float* bq1 = (const float*)d_in[4];
    const float* wq2 = (const float*)d_in[5];
    const float* bq2 = (const float*)d_in[6];
    const float* wk1 = (const float*)d_in[7];
    const float* bk1 = (const float*)d_in[8];
    const float* wk2 = (const float*)d_in[9];
    // d_in[10] = bk2: per-row constant in scores -> cancels in softmax.

    float* out  = (float*)d_out;
    const int B = in_sizes[0] / QD;  // 2048

    fused_attn<<<B, 256, 0, stream>>>(fwp, pwp, to, wq1, bq1, wq2, bq2,
                                      wk1, bk1, wk2,
                                      out, out + (size_t)B * DO);
}